// Round 7
// baseline (1862.180 us; speedup 1.0000x reference)
//
#include <hip/hip_runtime.h>
#include <math.h>

// KMeansGrouping: B=32, N=4096, D=256, K=24, 25 iters.
// Round 7: k_cluster rewrite. (a) deterministic ballot-prefix member-list
// compaction into LDS (ascending point order), (b) indexed, striped,
// unrolled accumulation loop (pipelined loads vs r6's serial bit-scan),
// (c) XCD-aware block mapping: all 24 cluster-blocks of a batch on one XCD
// so the batch's 4.2 MB feat slice stays L2-resident.
// k_assign (f32 scoring) + f64 trajectory state unchanged from r5/r6.

#define BATCH 32
#define NPTS 4096
#define DIM 256
#define NSLOT 24
#define NITER 25

// ---------------- K0: per-point inverse norm (f64) ----------------
__global__ __launch_bounds__(256) void k_norm(const float* __restrict__ feat,
                                              double* __restrict__ inv_norm) {
  int lane = threadIdx.x & 63;
  int wid = threadIdx.x >> 6;
  int p = blockIdx.x * 4 + wid; // one wave per point
  const float4 v = *(const float4*)(feat + (size_t)p * DIM + lane * 4);
  double s = (double)v.x * v.x + (double)v.y * v.y + (double)v.z * v.z + (double)v.w * v.w;
#pragma unroll
  for (int m = 32; m; m >>= 1) s += __shfl_xor(s, m);
  if (lane == 0) inv_norm[p] = 1.0 / fmax(sqrt(s), 1e-12);
}

__device__ __forceinline__ double block_sum_256(double v, double* red) {
#pragma unroll
  for (int m = 32; m; m >>= 1) v += __shfl_xor(v, m);
  int w = threadIdx.x >> 6;
  if ((threadIdx.x & 63) == 0) red[w] = v;
  __syncthreads();
  return red[0] + red[1] + red[2] + red[3];
}

// ---------------- K0b: initial centers (f64 + f32 [d][k]) + c_sq32 --------
// init_idx = floor(linspace(0, N-1, K)): idx_k = floor(k*4095/23).
__global__ __launch_bounds__(256) void k_init_centers(const float* __restrict__ feat,
                                                      const double* __restrict__ inv_norm,
                                                      double* __restrict__ centers,
                                                      float* __restrict__ cT32,
                                                      float* __restrict__ c_sq32) {
  __shared__ double red[4];
  int t = threadIdx.x, k = blockIdx.x, b = blockIdx.y;
  int idx = (int)((double)k * (NPTS - 1) / (NSLOT - 1));
  double v = (double)feat[((size_t)b * NPTS + idx) * DIM + t] * inv_norm[b * NPTS + idx];
  centers[((size_t)b * NSLOT + k) * DIM + t] = v;
  cT32[((size_t)b * DIM + t) * NSLOT + k] = (float)v;
  double s = block_sum_256(v * v, red);
  if (t == 0) c_sq32[b * NSLOT + k] = (float)s;
}

// ---------------- K0c: tiled transpose feat -> xT[b][d][n] (f32) ----------
__global__ __launch_bounds__(256) void k_transpose(const float* __restrict__ feat,
                                                   float* __restrict__ xT) {
  __shared__ float tile[64][65];
  int ix = threadIdx.x & 63, iy = threadIdx.x >> 6;
  int bx = blockIdx.x, by = blockIdx.y, b = blockIdx.z;
  const float* fb = feat + ((size_t)b * NPTS + bx * 64) * DIM + by * 64;
#pragma unroll
  for (int r = 0; r < 64; r += 4)
    tile[r + iy][ix] = fb[(size_t)(r + iy) * DIM + ix];
  __syncthreads();
  float* xb = xT + ((size_t)b * DIM + by * 64) * NPTS + bx * 64;
#pragma unroll
  for (int r = 0; r < 64; r += 4)
    xb[(size_t)(r + iy) * NPTS + ix] = tile[ix][r + iy];
}

// ---------------- K1: assignment (f32 scoring), quarter-D per wave --------
template <bool USE_T>
__global__ __launch_bounds__(256) void k_assign(const float* __restrict__ feat,
                                                const float* __restrict__ xT,
                                                const double* __restrict__ inv_norm,
                                                const float* __restrict__ cT32,
                                                const float* __restrict__ c_sq32,
                                                int* __restrict__ assign) {
  __shared__ float part[3][64][NSLOT + 1]; // 19200 B, odd lane stride
  int lane = threadIdx.x & 63;
  int q = __builtin_amdgcn_readfirstlane(threadIdx.x >> 6);
  int blk = blockIdx.x, b = blockIdx.y;
  int n = blk * 64 + lane;
  const float* cb = cT32 + ((size_t)b * DIM + q * 64) * NSLOT;

  float dot[NSLOT];
#pragma unroll
  for (int k = 0; k < NSLOT; ++k) dot[k] = 0.0f;

  for (int d = 0; d < 64; d += 4) {
    float x0, x1, x2, x3;
    if (USE_T) {
      const float* xp = xT + ((size_t)b * DIM + q * 64 + d) * NPTS + n;
      x0 = xp[0]; x1 = xp[NPTS]; x2 = xp[2 * NPTS]; x3 = xp[3 * NPTS];
    } else {
      float4 v = *(const float4*)(feat + ((size_t)b * NPTS + n) * DIM + q * 64 + d);
      x0 = v.x; x1 = v.y; x2 = v.z; x3 = v.w;
    }
    const float* cp = cb + (size_t)d * NSLOT; // wave-uniform -> s_load
#pragma unroll
    for (int k = 0; k < NSLOT; ++k) {
      float s = dot[k];
      s = fmaf(x0, cp[k], s);
      s = fmaf(x1, cp[NSLOT + k], s);
      s = fmaf(x2, cp[2 * NSLOT + k], s);
      s = fmaf(x3, cp[3 * NSLOT + k], s);
      dot[k] = s;
    }
  }

  if (q) {
#pragma unroll
    for (int k = 0; k < NSLOT; ++k) part[q - 1][lane][k] = dot[k];
  }
  __syncthreads();

  if (q == 0) {
    float inv = (float)inv_norm[b * NPTS + n];
    const float* csq = c_sq32 + b * NSLOT; // uniform -> s_load
    int a = 0;
    float best = 0.0f;
#pragma unroll
    for (int k = 0; k < NSLOT; ++k) {
      float df = dot[k] + part[0][lane][k] + part[1][lane][k] + part[2][lane][k];
      float s = csq[k] - 2.0f * (df * inv);
      if (k == 0) { best = s; }
      else if (s < best) { best = s; a = k; }
    }
    assign[b * NPTS + n] = a;
  }
}

// ---------------- K2: fused cluster sum + center update (v2) --------------
// 1D grid of 768; id -> (k,b) with all 24 k-blocks of batch b on XCD b&7
// (default round-robin dispatch: XCD = id % 8). Phase 1 builds the member
// list in LDS via ballot+prefix (ascending n, deterministic). Phase 2:
// indexed striped loop, unroll x2, coalesced float4 row loads (lane = 4 dims),
// f64 accumulate; cross-wave combine in fixed order.
__global__ __launch_bounds__(256) void k_cluster(const float* __restrict__ feat,
                                                 const double* __restrict__ inv_norm,
                                                 const int* __restrict__ assign,
                                                 double* __restrict__ centers,
                                                 float* __restrict__ cT32,
                                                 float* __restrict__ c_sq32) {
  __shared__ int list[NPTS];      // 16 KB
  __shared__ int wtot[4];
  __shared__ double part[4][DIM]; // 8 KB
  __shared__ double red[4];

  int id = blockIdx.x;
  int xcd = id & 7;
  int r = id >> 3;
  int k = r % NSLOT;
  int b = (r / NSLOT) * 8 + xcd;

  int t = threadIdx.x;
  int lane = t & 63;
  int w = __builtin_amdgcn_readfirstlane(t >> 6);

  // ---- phase 1: deterministic member-list compaction (ascending n) ----
  const int* ab = assign + b * NPTS;
  int base = 0; // block-uniform (all threads track identically)
  for (int rr = 0; rr < NPTS / 256; ++rr) {
    int a = ab[rr * 256 + t];
    bool m = (a == k);
    unsigned long long bal = __ballot(m);
    int rank = __popcll(bal & ((1ull << lane) - 1ull));
    if (lane == 0) wtot[w] = __popcll(bal);
    __syncthreads();
    int off = base;
#pragma unroll
    for (int w2 = 0; w2 < 3; ++w2)
      if (w2 < w) off += wtot[w2];
    if (m) list[off + rank] = rr * 256 + t;
    base += wtot[0] + wtot[1] + wtot[2] + wtot[3];
    __syncthreads();
  }
  int mcount = base;

  // ---- phase 2: striped indexed accumulation, unroll x2 ----
  const float* fb = feat + (size_t)b * NPTS * DIM + lane * 4;
  const double* ib = inv_norm + b * NPTS;
  double a0 = 0.0, a1 = 0.0, a2 = 0.0, a3 = 0.0;

  for (int i = w; i < mcount; i += 8) {
    int n0 = __builtin_amdgcn_readfirstlane(list[i]);
    bool have1 = (i + 4) < mcount;
    int n1 = __builtin_amdgcn_readfirstlane(have1 ? list[i + 4] : list[i]);
    float4 v0 = *(const float4*)(fb + (size_t)n0 * DIM);
    float4 v1 = *(const float4*)(fb + (size_t)n1 * DIM);
    double i0 = ib[n0];
    double i1 = ib[n1];
    a0 += (double)v0.x * i0; a1 += (double)v0.y * i0;
    a2 += (double)v0.z * i0; a3 += (double)v0.w * i0;
    if (have1) {
      a0 += (double)v1.x * i1; a1 += (double)v1.y * i1;
      a2 += (double)v1.z * i1; a3 += (double)v1.w * i1;
    }
  }

  part[w][lane * 4 + 0] = a0;
  part[w][lane * 4 + 1] = a1;
  part[w][lane * 4 + 2] = a2;
  part[w][lane * 4 + 3] = a3;
  __syncthreads();

  double s = ((part[0][t] + part[1][t]) + part[2][t]) + part[3][t]; // fixed order

  size_t ci = ((size_t)b * NSLOT + k) * DIM + t;
  double nc = (mcount > 0) ? (s / (double)mcount) : centers[ci];
  centers[ci] = nc;
  cT32[((size_t)b * DIM + t) * NSLOT + k] = (float)nc;
  double sq = block_sum_256(nc * nc, red);
  if (t == 0) c_sq32[b * NSLOT + k] = (float)sq;
}

// ---------------- K4: masks + centers output ----------------
__global__ __launch_bounds__(256) void k_mask(const int* __restrict__ assign,
                                              float* __restrict__ masks) {
  int t = threadIdx.x, nc = blockIdx.x, k = blockIdx.y, b = blockIdx.z;
  int n = nc * 256 + t;
  masks[((size_t)b * NSLOT + k) * NPTS + n] = (assign[b * NPTS + n] == k) ? 1.0f : 0.0f;
}

__global__ __launch_bounds__(256) void k_copyc(const double* __restrict__ centers,
                                               float* __restrict__ out_centers) {
  int t = threadIdx.x, k = blockIdx.x, b = blockIdx.y;
  size_t i = ((size_t)b * NSLOT + k) * DIM + t;
  out_centers[i] = (float)centers[i];
}

extern "C" void kernel_launch(void* const* d_in, const int* in_sizes, int n_in,
                              void* d_out, int out_size, void* d_ws, size_t ws_size,
                              hipStream_t stream) {
  (void)in_sizes; (void)n_in; (void)out_size;
  const float* feat = (const float*)d_in[0];
  float* out_centers = (float*)d_out;                           // (32,24,256)
  float* out_masks = out_centers + (size_t)BATCH * NSLOT * DIM; // (32,24,4096)

  // workspace: ~4 MB fixed + optional 134 MB xT tail.
  char* ws = (char*)d_ws;
  double* inv_norm = (double*)ws; ws += (size_t)BATCH * NPTS * 8;        // 1.0 MB
  double* centers  = (double*)ws; ws += (size_t)BATCH * NSLOT * DIM * 8; // 1.5 MB
  float* cT32      = (float*)ws;  ws += (size_t)BATCH * DIM * NSLOT * 4; // 0.77 MB
  float* c_sq32    = (float*)ws;  ws += (size_t)BATCH * NSLOT * 4;       // 3 KB
  int* assign      = (int*)ws;    ws += (size_t)BATCH * NPTS * 4;        // 0.5 MB
  float* xT        = (float*)ws;
  size_t need_xT = (size_t)(ws - (char*)d_ws) + (size_t)BATCH * DIM * NPTS * 4; // ~138 MB
  bool useT = ws_size >= need_xT;

  k_norm<<<BATCH * NPTS / 4, 256, 0, stream>>>(feat, inv_norm);
  k_init_centers<<<dim3(NSLOT, BATCH), 256, 0, stream>>>(feat, inv_norm, centers,
                                                         cT32, c_sq32);
  if (useT)
    k_transpose<<<dim3(NPTS / 64, DIM / 64, BATCH), 256, 0, stream>>>(feat, xT);

  for (int it = 0; it <= NITER; ++it) {
    if (useT)
      k_assign<true><<<dim3(NPTS / 64, BATCH), 256, 0, stream>>>(feat, xT, inv_norm,
                                                                 cT32, c_sq32, assign);
    else
      k_assign<false><<<dim3(NPTS / 64, BATCH), 256, 0, stream>>>(feat, xT, inv_norm,
                                                                  cT32, c_sq32, assign);
    if (it == NITER) break; // final assignment only
    k_cluster<<<NSLOT * BATCH, 256, 0, stream>>>(feat, inv_norm, assign,
                                                 centers, cT32, c_sq32);
  }

  k_mask<<<dim3(NPTS / 256, NSLOT, BATCH), 256, 0, stream>>>(assign, out_masks);
  k_copyc<<<dim3(NSLOT, BATCH), 256, 0, stream>>>(centers, out_centers);
}

// Round 8
// 1729.797 us; speedup vs baseline: 1.0765x; 1.0765x over previous
//
#include <hip/hip_runtime.h>
#include <math.h>

// KMeansGrouping: B=32, N=4096, D=256, K=24, 25 iters.
// Round 8: k_cluster load-balance fix -- split x4 along points (3072 blocks,
// each owns a contiguous 1024-pt quarter of one (k,b)): straggler work /4,
// blocks/CU 3->8+, 4 rows in flight. Partials (f64) + counts combined by tiny
// k_upd2 in fixed order (reassociation-only vs r7 -- the class proven safe in
// r4/r5/r6/r7). k_assign d-loop deepened 4->8 loads (bit-identical scores).
// Trajectory state f64 and all summands unchanged.

#define BATCH 32
#define NPTS 4096
#define DIM 256
#define NSLOT 24
#define NITER 25
#define QPTS 1024 // points per k_cluster4 block

// ---------------- K0: per-point inverse norm (f64) ----------------
__global__ __launch_bounds__(256) void k_norm(const float* __restrict__ feat,
                                              double* __restrict__ inv_norm) {
  int lane = threadIdx.x & 63;
  int wid = threadIdx.x >> 6;
  int p = blockIdx.x * 4 + wid; // one wave per point
  const float4 v = *(const float4*)(feat + (size_t)p * DIM + lane * 4);
  double s = (double)v.x * v.x + (double)v.y * v.y + (double)v.z * v.z + (double)v.w * v.w;
#pragma unroll
  for (int m = 32; m; m >>= 1) s += __shfl_xor(s, m);
  if (lane == 0) inv_norm[p] = 1.0 / fmax(sqrt(s), 1e-12);
}

__device__ __forceinline__ double block_sum_256(double v, double* red) {
#pragma unroll
  for (int m = 32; m; m >>= 1) v += __shfl_xor(v, m);
  int w = threadIdx.x >> 6;
  if ((threadIdx.x & 63) == 0) red[w] = v;
  __syncthreads();
  return red[0] + red[1] + red[2] + red[3];
}

// ---------------- K0b: initial centers (f64 + f32 [d][k]) + c_sq32 --------
// init_idx = floor(linspace(0, N-1, K)): idx_k = floor(k*4095/23).
__global__ __launch_bounds__(256) void k_init_centers(const float* __restrict__ feat,
                                                      const double* __restrict__ inv_norm,
                                                      double* __restrict__ centers,
                                                      float* __restrict__ cT32,
                                                      float* __restrict__ c_sq32) {
  __shared__ double red[4];
  int t = threadIdx.x, k = blockIdx.x, b = blockIdx.y;
  int idx = (int)((double)k * (NPTS - 1) / (NSLOT - 1));
  double v = (double)feat[((size_t)b * NPTS + idx) * DIM + t] * inv_norm[b * NPTS + idx];
  centers[((size_t)b * NSLOT + k) * DIM + t] = v;
  cT32[((size_t)b * DIM + t) * NSLOT + k] = (float)v;
  double s = block_sum_256(v * v, red);
  if (t == 0) c_sq32[b * NSLOT + k] = (float)s;
}

// ---------------- K0c: tiled transpose feat -> xT[b][d][n] (f32) ----------
__global__ __launch_bounds__(256) void k_transpose(const float* __restrict__ feat,
                                                   float* __restrict__ xT) {
  __shared__ float tile[64][65];
  int ix = threadIdx.x & 63, iy = threadIdx.x >> 6;
  int bx = blockIdx.x, by = blockIdx.y, b = blockIdx.z;
  const float* fb = feat + ((size_t)b * NPTS + bx * 64) * DIM + by * 64;
#pragma unroll
  for (int r = 0; r < 64; r += 4)
    tile[r + iy][ix] = fb[(size_t)(r + iy) * DIM + ix];
  __syncthreads();
  float* xb = xT + ((size_t)b * DIM + by * 64) * NPTS + bx * 64;
#pragma unroll
  for (int r = 0; r < 64; r += 4)
    xb[(size_t)(r + iy) * NPTS + ix] = tile[ix][r + iy];
}

// ---------------- K1: assignment (f32 scoring), quarter-D per wave --------
// d-loop processes 8 dims/iter (8 independent loads in flight); per-dot[k]
// accumulation order stays d-ascending -> bit-identical to rounds 5-7.
template <bool USE_T>
__global__ __launch_bounds__(256) void k_assign(const float* __restrict__ feat,
                                                const float* __restrict__ xT,
                                                const double* __restrict__ inv_norm,
                                                const float* __restrict__ cT32,
                                                const float* __restrict__ c_sq32,
                                                int* __restrict__ assign) {
  __shared__ float part[3][64][NSLOT + 1]; // 19200 B, odd lane stride
  int lane = threadIdx.x & 63;
  int q = __builtin_amdgcn_readfirstlane(threadIdx.x >> 6);
  int blk = blockIdx.x, b = blockIdx.y;
  int n = blk * 64 + lane;
  const float* cb = cT32 + ((size_t)b * DIM + q * 64) * NSLOT;

  float dot[NSLOT];
#pragma unroll
  for (int k = 0; k < NSLOT; ++k) dot[k] = 0.0f;

  for (int d = 0; d < 64; d += 8) {
    float x[8];
    if (USE_T) {
      const float* xp = xT + ((size_t)b * DIM + q * 64 + d) * NPTS + n;
#pragma unroll
      for (int j = 0; j < 8; ++j) x[j] = xp[(size_t)j * NPTS];
    } else {
      float4 v = *(const float4*)(feat + ((size_t)b * NPTS + n) * DIM + q * 64 + d);
      float4 u = *(const float4*)(feat + ((size_t)b * NPTS + n) * DIM + q * 64 + d + 4);
      x[0] = v.x; x[1] = v.y; x[2] = v.z; x[3] = v.w;
      x[4] = u.x; x[5] = u.y; x[6] = u.z; x[7] = u.w;
    }
    const float* cp = cb + (size_t)d * NSLOT; // wave-uniform -> s_load
#pragma unroll
    for (int k = 0; k < NSLOT; ++k) {
      float s = dot[k];
#pragma unroll
      for (int j = 0; j < 8; ++j) s = fmaf(x[j], cp[j * NSLOT + k], s);
      dot[k] = s;
    }
  }

  if (q) {
#pragma unroll
    for (int k = 0; k < NSLOT; ++k) part[q - 1][lane][k] = dot[k];
  }
  __syncthreads();

  if (q == 0) {
    float inv = (float)inv_norm[b * NPTS + n];
    const float* csq = c_sq32 + b * NSLOT; // uniform -> s_load
    int a = 0;
    float best = 0.0f;
#pragma unroll
    for (int k = 0; k < NSLOT; ++k) {
      float df = dot[k] + part[0][lane][k] + part[1][lane][k] + part[2][lane][k];
      float s = csq[k] - 2.0f * (df * inv);
      if (k == 0) { best = s; }
      else if (s < best) { best = s; a = k; }
    }
    assign[b * NPTS + n] = a;
  }
}

// ---------------- K2: cluster partial sums, x4 point-split ----------------
// Block id -> (b,k,q): points [q*1024, q*1024+1024). Phase 1: deterministic
// ballot-prefix compaction (ascending n) into ushort list. Phase 2: striped
// indexed loop, 4 rows in flight/wave, coalesced float4 row loads, f64
// accumulate; wave partials combined in fixed order; write psumG + count.
__global__ __launch_bounds__(256) void k_cluster4(const float* __restrict__ feat,
                                                  const double* __restrict__ inv_norm,
                                                  const int* __restrict__ assign,
                                                  double* __restrict__ psumG,
                                                  int* __restrict__ cntG) {
  __shared__ unsigned short list[QPTS]; // 2 KB
  __shared__ int wtot[4];
  __shared__ double part[4][DIM];       // 8 KB

  int id = blockIdx.x; // ((b*NSLOT)+k)*4+q
  int q = id & 3;
  int r = id >> 2;
  int k = r % NSLOT;
  int b = r / NSLOT;

  int t = threadIdx.x;
  int lane = t & 63;
  int w = __builtin_amdgcn_readfirstlane(t >> 6);

  // ---- phase 1: compaction of this quarter's members (ascending n) ----
  const int* ab = assign + b * NPTS + q * QPTS;
  int base = 0; // block-uniform
  for (int rr = 0; rr < QPTS / 256; ++rr) {
    bool m = (ab[rr * 256 + t] == k);
    unsigned long long bal = __ballot(m);
    int rank = __popcll(bal & ((1ull << lane) - 1ull));
    if (lane == 0) wtot[w] = __popcll(bal);
    __syncthreads();
    int off = base;
#pragma unroll
    for (int w2 = 0; w2 < 3; ++w2)
      if (w2 < w) off += wtot[w2];
    if (m) list[off + rank] = (unsigned short)(rr * 256 + t);
    base += wtot[0] + wtot[1] + wtot[2] + wtot[3];
    __syncthreads();
  }
  int mcount = base;

  // ---- phase 2: striped, 4 rows in flight per wave ----
  const float* fb = feat + ((size_t)b * NPTS + q * QPTS) * DIM + lane * 4;
  const double* ib = inv_norm + b * NPTS + q * QPTS;
  double a0 = 0.0, a1 = 0.0, a2 = 0.0, a3 = 0.0;

  for (int i = w; i < mcount; i += 16) {
    bool h1 = (i + 4) < mcount, h2 = (i + 8) < mcount, h3 = (i + 12) < mcount;
    int n0 = __builtin_amdgcn_readfirstlane((int)list[i]);
    int n1 = __builtin_amdgcn_readfirstlane((int)list[h1 ? i + 4 : i]);
    int n2 = __builtin_amdgcn_readfirstlane((int)list[h2 ? i + 8 : i]);
    int n3 = __builtin_amdgcn_readfirstlane((int)list[h3 ? i + 12 : i]);
    float4 v0 = *(const float4*)(fb + (size_t)n0 * DIM);
    float4 v1 = *(const float4*)(fb + (size_t)n1 * DIM);
    float4 v2 = *(const float4*)(fb + (size_t)n2 * DIM);
    float4 v3 = *(const float4*)(fb + (size_t)n3 * DIM);
    double i0 = ib[n0], i1 = ib[n1], i2 = ib[n2], i3 = ib[n3];
    a0 += (double)v0.x * i0; a1 += (double)v0.y * i0;
    a2 += (double)v0.z * i0; a3 += (double)v0.w * i0;
    if (h1) { a0 += (double)v1.x * i1; a1 += (double)v1.y * i1;
              a2 += (double)v1.z * i1; a3 += (double)v1.w * i1; }
    if (h2) { a0 += (double)v2.x * i2; a1 += (double)v2.y * i2;
              a2 += (double)v2.z * i2; a3 += (double)v2.w * i2; }
    if (h3) { a0 += (double)v3.x * i3; a1 += (double)v3.y * i3;
              a2 += (double)v3.z * i3; a3 += (double)v3.w * i3; }
  }

  part[w][lane * 4 + 0] = a0;
  part[w][lane * 4 + 1] = a1;
  part[w][lane * 4 + 2] = a2;
  part[w][lane * 4 + 3] = a3;
  __syncthreads();

  double s = ((part[0][t] + part[1][t]) + part[2][t]) + part[3][t]; // fixed order
  psumG[(size_t)id * DIM + t] = s;
  if (t == 0) cntG[id] = mcount;
}

// ---------------- K3: combine quarters -> new centers + cT32 + c_sq -------
__global__ __launch_bounds__(256) void k_upd2(const double* __restrict__ psumG,
                                              const int* __restrict__ cntG,
                                              double* __restrict__ centers,
                                              float* __restrict__ cT32,
                                              float* __restrict__ c_sq32) {
  __shared__ double red[4];
  int t = threadIdx.x, k = blockIdx.x, b = blockIdx.y;
  int id = (b * NSLOT + k) * 4;
  const double* p = psumG + (size_t)id * DIM;
  double s = ((p[t] + p[DIM + t]) + p[2 * DIM + t]) + p[3 * DIM + t]; // fixed order
  int cnt = cntG[id] + cntG[id + 1] + cntG[id + 2] + cntG[id + 3];

  size_t ci = ((size_t)b * NSLOT + k) * DIM + t;
  double nc = (cnt > 0) ? (s / (double)cnt) : centers[ci];
  centers[ci] = nc;
  cT32[((size_t)b * DIM + t) * NSLOT + k] = (float)nc;
  double sq = block_sum_256(nc * nc, red);
  if (t == 0) c_sq32[b * NSLOT + k] = (float)sq;
}

// ---------------- K4: masks + centers output ----------------
__global__ __launch_bounds__(256) void k_mask(const int* __restrict__ assign,
                                              float* __restrict__ masks) {
  int t = threadIdx.x, nc = blockIdx.x, k = blockIdx.y, b = blockIdx.z;
  int n = nc * 256 + t;
  masks[((size_t)b * NSLOT + k) * NPTS + n] = (assign[b * NPTS + n] == k) ? 1.0f : 0.0f;
}

__global__ __launch_bounds__(256) void k_copyc(const double* __restrict__ centers,
                                               float* __restrict__ out_centers) {
  int t = threadIdx.x, k = blockIdx.x, b = blockIdx.y;
  size_t i = ((size_t)b * NSLOT + k) * DIM + t;
  out_centers[i] = (float)centers[i];
}

extern "C" void kernel_launch(void* const* d_in, const int* in_sizes, int n_in,
                              void* d_out, int out_size, void* d_ws, size_t ws_size,
                              hipStream_t stream) {
  (void)in_sizes; (void)n_in; (void)out_size;
  const float* feat = (const float*)d_in[0];
  float* out_centers = (float*)d_out;                           // (32,24,256)
  float* out_masks = out_centers + (size_t)BATCH * NSLOT * DIM; // (32,24,4096)

  // workspace: ~10.1 MB fixed + optional 134 MB xT tail.
  char* ws = (char*)d_ws;
  double* inv_norm = (double*)ws; ws += (size_t)BATCH * NPTS * 8;            // 1.0 MB
  double* centers  = (double*)ws; ws += (size_t)BATCH * NSLOT * DIM * 8;     // 1.5 MB
  float* cT32      = (float*)ws;  ws += (size_t)BATCH * DIM * NSLOT * 4;     // 0.77 MB
  float* c_sq32    = (float*)ws;  ws += (size_t)BATCH * NSLOT * 4;           // 3 KB
  int* assign      = (int*)ws;    ws += (size_t)BATCH * NPTS * 4;            // 0.5 MB
  double* psumG    = (double*)ws; ws += (size_t)BATCH * NSLOT * 4 * DIM * 8; // 6.3 MB
  int* cntG        = (int*)ws;    ws += (size_t)BATCH * NSLOT * 4 * 4;       // 12 KB
  float* xT        = (float*)ws;
  size_t need_xT = (size_t)(ws - (char*)d_ws) + (size_t)BATCH * DIM * NPTS * 4; // ~144 MB
  bool useT = ws_size >= need_xT;

  k_norm<<<BATCH * NPTS / 4, 256, 0, stream>>>(feat, inv_norm);
  k_init_centers<<<dim3(NSLOT, BATCH), 256, 0, stream>>>(feat, inv_norm, centers,
                                                         cT32, c_sq32);
  if (useT)
    k_transpose<<<dim3(NPTS / 64, DIM / 64, BATCH), 256, 0, stream>>>(feat, xT);

  for (int it = 0; it <= NITER; ++it) {
    if (useT)
      k_assign<true><<<dim3(NPTS / 64, BATCH), 256, 0, stream>>>(feat, xT, inv_norm,
                                                                 cT32, c_sq32, assign);
    else
      k_assign<false><<<dim3(NPTS / 64, BATCH), 256, 0, stream>>>(feat, xT, inv_norm,
                                                                  cT32, c_sq32, assign);
    if (it == NITER) break; // final assignment only
    k_cluster4<<<NSLOT * BATCH * 4, 256, 0, stream>>>(feat, inv_norm, assign,
                                                      psumG, cntG);
    k_upd2<<<dim3(NSLOT, BATCH), 256, 0, stream>>>(psumG, cntG, centers, cT32, c_sq32);
  }

  k_mask<<<dim3(NPTS / 256, NSLOT, BATCH), 256, 0, stream>>>(assign, out_masks);
  k_copyc<<<dim3(NSLOT, BATCH), 256, 0, stream>>>(centers, out_centers);
}